// Round 8
// baseline (88.931 us; speedup 1.0000x reference)
//
#include <hip/hip_runtime.h>

// out: 4 tensors (32, 20, 14, 14, 14, 14) fp32 concatenated.
// Block = (n, q, d2); each block writes 4 contiguous chunks of 14*196 floats.
// R7 = R6 + hand-pipelined main: batch loads -> compute 12 float4 regs -> burst stores.
//   out_p[d3][ps] = F_i[d3][ps] * G_j[d3][ps]
//   F_i = A_i[d3,d4]*B_i[d3,d5];  A_i = 0.5*cor_i[0,pc]*cor_i[1+q,pc]*cor_i[23+d4,pc]
//   B_i = cor_i[37+d5,pc];        G_j = T_j[ps]*cen_j[37+d3,ps]
//   T_j[ps] = cen_j[0,ps]*cen_j[1+q,ps]*cen_j[23+d2,ps]
// p1=F1*G1  p2=F2*G1  p3=F1*G2  p4=F2*G2

#define S_PER 24586240u            // 32*20*14^4 elements per tensor
#define TSTRIDE (51 * 196)
#define N_STRIDE (204 * 196)
#define NBLK 8960u                 // 32*20*14
#define NXCD 8u
#define BLK_PER_XCD (NBLK / NXCD)  // 1120

__global__ __launch_bounds__(256) void plnet_kernel(const float* __restrict__ in,
                                                    float* __restrict__ out) {
    __shared__ __align__(16) float sT1[196];
    __shared__ __align__(16) float sT2[196];
    __shared__ float sA1[196], sA2[196];   // [d3*14 + d4]
    __shared__ float sB1[196], sB2[196];   // [d3*14 + d5]

    const unsigned raw = blockIdx.x;
    const unsigned b   = (raw % NXCD) * BLK_PER_XCD + raw / NXCD;

    const unsigned d2 = b % 14u;
    const unsigned nq = b / 14u;
    const unsigned q  = nq % 20u;
    const unsigned n  = nq / 20u;

    const float* g    = in + (size_t)n * N_STRIDE;
    const float* cor1 = g;
    const float* cor2 = g + TSTRIDE;
    const float* cen1 = g + 2 * TSTRIDE;
    const float* cen2 = g + 3 * TSTRIDE;

    const unsigned tid = threadIdx.x;

    // ---- Prologue: 6 small LDS tables, one barrier ----
    if (tid < 196u) {
        const unsigned ps = tid;
        sT1[ps] = cen1[ps] * cen1[(1u + q) * 196u + ps] * cen1[(23u + d2) * 196u + ps];
        sT2[ps] = cen2[ps] * cen2[(1u + q) * 196u + ps] * cen2[(23u + d2) * 196u + ps];
        const unsigned d3 = ps / 14u;
        const unsigned k  = ps - d3 * 14u;
        const unsigned pc = d2 * 14u + d3;
        const float k1 = 0.5f * cor1[pc] * cor1[(1u + q) * 196u + pc];
        const float k2 = 0.5f * cor2[pc] * cor2[(1u + q) * 196u + pc];
        sA1[ps] = k1 * cor1[(23u + k) * 196u + pc];
        sA2[ps] = k2 * cor2[(23u + k) * 196u + pc];
        sB1[ps] = cor1[(37u + k) * 196u + pc];
        sB2[ps] = cor2[(37u + k) * 196u + pc];
    }
    __syncthreads();

    // ---- Hand-pipelined main: 3 items/thread, batch loads, burst stores ----
    const bool valid2 = (tid < 174u);      // 686 = 256 + 256 + 174

    unsigned cs[3], d3s[3], es[3];
#pragma unroll
    for (int k = 0; k < 3; ++k) {
        unsigned c = tid + 256u * (unsigned)k;
        if (k == 2 && !valid2) c = tid;    // safe dummy
        const unsigned d3 = c / 49u;
        const unsigned f  = c - d3 * 49u;
        cs[k] = c; d3s[k] = d3; es[k] = 4u * f;
    }

    // Phase A: all global loads issued together
    float4 v1[3], v2[3];
#pragma unroll
    for (int k = 0; k < 3; ++k) {
        v1[k] = *(const float4*)&cen1[(37u + d3s[k]) * 196u + es[k]];
        v2[k] = *(const float4*)&cen2[(37u + d3s[k]) * 196u + es[k]];
    }

    // Phase B: LDS + compute into 12 float4 registers
    float4 r1[3], r2[3], r3[3], r4[3];
#pragma unroll
    for (int k = 0; k < 3; ++k) {
        const unsigned d3 = d3s[k], e = es[k];
        const float4 t1 = *(const float4*)&sT1[e];
        const float4 t2 = *(const float4*)&sT2[e];
        const float4 G1 = make_float4(t1.x * v1[k].x, t1.y * v1[k].y,
                                      t1.z * v1[k].z, t1.w * v1[k].w);
        const float4 G2 = make_float4(t2.x * v2[k].x, t2.y * v2[k].y,
                                      t2.z * v2[k].z, t2.w * v2[k].w);
        unsigned d4 = e / 14u;
        unsigned d5 = e - d4 * 14u;
        float F1[4], F2[4];
#pragma unroll
        for (int l = 0; l < 4; ++l) {
            F1[l] = sA1[d3 * 14u + d4] * sB1[d3 * 14u + d5];
            F2[l] = sA2[d3 * 14u + d4] * sB2[d3 * 14u + d5];
            ++d5;
            const unsigned carry = (d5 == 14u);
            d4 += carry;
            d5 = carry ? 0u : d5;
        }
        r1[k] = make_float4(F1[0] * G1.x, F1[1] * G1.y, F1[2] * G1.z, F1[3] * G1.w);
        r2[k] = make_float4(F2[0] * G1.x, F2[1] * G1.y, F2[2] * G1.z, F2[3] * G1.w);
        r3[k] = make_float4(F1[0] * G2.x, F1[1] * G2.y, F1[2] * G2.z, F1[3] * G2.w);
        r4[k] = make_float4(F2[0] * G2.x, F2[1] * G2.y, F2[2] * G2.z, F2[3] * G2.w);
    }

    // Phase C: burst stores, grouped per tensor, ascending address
    const size_t chunk = ((size_t)(n * 20u + q) * 196u + d2 * 14u) * 196u;
    float4* o1 = (float4*)(out + chunk);
    float4* o2 = (float4*)(out + (size_t)S_PER + chunk);
    float4* o3 = (float4*)(out + 2u * (size_t)S_PER + chunk);
    float4* o4 = (float4*)(out + 3u * (size_t)S_PER + chunk);

    o1[cs[0]] = r1[0]; o1[cs[1]] = r1[1]; if (valid2) o1[cs[2]] = r1[2];
    o2[cs[0]] = r2[0]; o2[cs[1]] = r2[1]; if (valid2) o2[cs[2]] = r2[2];
    o3[cs[0]] = r3[0]; o3[cs[1]] = r3[1]; if (valid2) o3[cs[2]] = r3[2];
    o4[cs[0]] = r4[0]; o4[cs[1]] = r4[1]; if (valid2) o4[cs[2]] = r4[2];
}

extern "C" void kernel_launch(void* const* d_in, const int* in_sizes, int n_in,
                              void* d_out, int out_size, void* d_ws, size_t ws_size,
                              hipStream_t stream) {
    const float* in = (const float*)d_in[0];
    float* out = (float*)d_out;
    dim3 grid(NBLK);               // one block per (n, q, d2), XCD-remapped inside
    dim3 block(256);
    plnet_kernel<<<grid, block, 0, stream>>>(in, out);
}